// Round 3
// baseline (403.849 us; speedup 1.0000x reference)
//
#include <hip/hip_runtime.h>
#include <hip/hip_bf16.h>
#include <stdint.h>

// Problem constants (N,C,H,W = 4,128,64,64)
#define NB 4
#define CH 128
#define LL 4096   // H*W

typedef __attribute__((ext_vector_type(8))) short short8;   // 8 bf16 (4 VGPRs) MFMA A/B frag
typedef __attribute__((ext_vector_type(4))) short short4b;  // 4 bf16 (8B)
typedef __attribute__((ext_vector_type(4))) float floatx4;  // MFMA C/D frag

static __device__ __forceinline__ short f2bf(float f) {
    // round-to-nearest-even fp32 -> bf16 (inputs are finite, no NaN handling needed)
    uint32_t u = __float_as_uint(f);
    u += 0x7fffu + ((u >> 16) & 1u);
    return (short)(u >> 16);
}

// ---------------------------------------------------------------------------
// Kernel 1: QKV projection (1x1 conv == per-pixel channel mixing).
// Writes Qt[n][l][c] (bf16), Kt[n][l][c] (bf16, pre-scaled by 1/sqrt(C)),
// Vn[n][c][l] (bf16).
// grid = NB * 8(o-blocks of 16) * 16(l-chunks of 256) = 512 blocks, 256 thr.
// VALU fp32: 1.6 GFLOP total -> ~10us floor at vector peak. MFMA-ize later.
// ---------------------------------------------------------------------------
__global__ __launch_bounds__(256) void proj_kernel(
    const float* __restrict__ x,
    const float* __restrict__ Wq, const float* __restrict__ bq,
    const float* __restrict__ Wk, const float* __restrict__ bk,
    const float* __restrict__ Wv, const float* __restrict__ bv,
    short* __restrict__ Qt, short* __restrict__ Kt, short* __restrict__ Vn)
{
    const int b   = blockIdx.x;
    const int n   = b >> 7;            // 128 blocks per n
    const int rem = b & 127;
    const int o0  = (rem >> 4) * 16;   // 8 o-blocks of 16 outputs
    const int l   = ((rem & 15) << 8) + threadIdx.x;  // 16 l-chunks of 256

    const float* xp = x + ((size_t)n * CH) * LL + l;

    float aq[16], ak[16], av[16];
    #pragma unroll
    for (int u = 0; u < 16; ++u) {
        aq[u] = bq[o0 + u];
        ak[u] = bk[o0 + u];
        av[u] = bv[o0 + u];
    }

    for (int c = 0; c < CH; ++c) {
        const float xv = xp[(size_t)c * LL];   // coalesced across lanes
        #pragma unroll
        for (int u = 0; u < 16; ++u) {
            // W indices are wave-uniform (o0 from blockIdx, c scalar loop) -> s_load
            aq[u] += Wq[(o0 + u) * CH + c] * xv;
            ak[u] += Wk[(o0 + u) * CH + c] * xv;
            av[u] += Wv[(o0 + u) * CH + c] * xv;
        }
    }

    const float scale = 0.08838834764831845f;  // 1/sqrt(128), folded into K
    short8 q0, q1, k0, k1;
    #pragma unroll
    for (int u = 0; u < 8; ++u) {
        q0[u] = f2bf(aq[u]);      q1[u] = f2bf(aq[u + 8]);
        k0[u] = f2bf(ak[u] * scale); k1[u] = f2bf(ak[u + 8] * scale);
    }
    short* qrow = Qt + ((size_t)n * LL + l) * CH + o0;
    short* krow = Kt + ((size_t)n * LL + l) * CH + o0;
    *(short8*)(void*)qrow       = q0;
    *(short8*)(void*)(qrow + 8) = q1;
    *(short8*)(void*)krow       = k0;
    *(short8*)(void*)(krow + 8) = k1;
    #pragma unroll
    for (int u = 0; u < 16; ++u)   // coalesced across lanes (l contiguous)
        Vn[((size_t)n * CH + o0 + u) * LL + l] = f2bf(av[u]);
}

// ---------------------------------------------------------------------------
// Kernel 2: per-row softmax denominators. D[l] = sum_m exp(S[l,m]),
// S = Kt (scaled) dot Q. No max subtraction: S ~ N(0,1), |S|max << 80.
// Stores reciprocal 1/D.  grid = NB * (LL/64) = 256 blocks, 4 waves each.
// Wave w owns rows [l0+16w, l0+16w+16); K A-frags stay in registers for the
// whole m sweep; Q B-frags stream from global (L1-shared across the 4 waves).
// ---------------------------------------------------------------------------
__global__ __launch_bounds__(256) void rowsum_kernel(
    const short* __restrict__ Qt, const short* __restrict__ Kt,
    float* __restrict__ Drcp)
{
    const int b    = blockIdx.x;
    const int n    = b >> 6;
    const int l0   = (b & 63) << 6;
    const int wave = threadIdx.x >> 6;
    const int lane = threadIdx.x & 63;
    const int quad = lane >> 4;
    const int mc   = lane & 15;
    const int lw   = l0 + wave * 16;

    // A-frag: A[m=mc][k=32s+8q+j] = K[l=lw+mc][c]
    const short* kb = Kt + ((size_t)n * LL + lw + mc) * CH + quad * 8;
    short8 kf[4];
    #pragma unroll
    for (int s = 0; s < 4; ++s) kf[s] = *(const short8*)(const void*)(kb + 32 * s);

    const short* Qn = Qt + (size_t)n * LL * CH;
    float rs[4] = {0.f, 0.f, 0.f, 0.f};

    #pragma unroll 2
    for (int m0 = 0; m0 < LL; m0 += 16) {
        const short* qb = Qn + ((size_t)(m0 + mc)) * CH + quad * 8;
        floatx4 acc = {0.f, 0.f, 0.f, 0.f};
        #pragma unroll
        for (int s = 0; s < 4; ++s)
            acc = __builtin_amdgcn_mfma_f32_16x16x32_bf16(
                kf[s], *(const short8*)(const void*)(qb + 32 * s), acc, 0, 0, 0);
        #pragma unroll
        for (int r = 0; r < 4; ++r) rs[r] += __expf(acc[r]);
    }

    // reduce over the 16 column-lanes (C-layout: col = lane&15)
    #pragma unroll
    for (int r = 0; r < 4; ++r) {
        float v = rs[r];
        v += __shfl_xor(v, 1);
        v += __shfl_xor(v, 2);
        v += __shfl_xor(v, 4);
        v += __shfl_xor(v, 8);
        rs[r] = v;
    }
    if (mc == 0) {
        #pragma unroll
        for (int r = 0; r < 4; ++r)   // C-layout row = quad*4 + r
            Drcp[(size_t)n * LL + lw + quad * 4 + r] = 1.0f / rs[r];
    }
}

// ---------------------------------------------------------------------------
// Kernel 3: O[c,m] = sum_l V[c,l] * exp(S[l,m]) * Drcp[l];  out = x + O.
// grid = NB * (LL/32) = 512 blocks (2 blocks/CU), 4 waves, m-block = 32.
// Per l-step of 64: phase1 each wave computes 16 S-rows x 32 cols via MFMA,
// applies exp*rcpD, writes bf16 P to LDS in [m][l] (B-operand) layout;
// phase2 V(A) x P(B) MFMA accumulates the [128 x 32] output tile.
// Q B-frags for the m-block are register-resident across the whole l loop.
// LDS row stride 72 shorts = 144 B = 9*16 B: keeps short8 (16 B) accesses
// aligned for every row while shifting banks by 4 per row.
// ---------------------------------------------------------------------------
__global__ __launch_bounds__(256) void attn_out_kernel(
    const short* __restrict__ Qt, const short* __restrict__ Kt,
    const short* __restrict__ Vn, const float* __restrict__ Drcp,
    const float* __restrict__ x, float* __restrict__ out)
{
    const int b    = blockIdx.x;
    const int n    = b >> 7;            // 128 m-blocks per n
    const int m0   = (b & 127) << 5;
    const int wave = threadIdx.x >> 6;
    const int lane = threadIdx.x & 63;
    const int quad = lane >> 4;
    const int mc   = lane & 15;
    const int cw   = wave * 32;         // wave's 32 output channels

    __shared__ short P[32][72];         // [m][l] bf16, +8 pad

    const short* Qn = Qt + (size_t)n * LL * CH;
    const short* Kn = Kt + (size_t)n * LL * CH;
    const short* Vb = Vn + (size_t)n * CH * LL;
    const float* Dn = Drcp + (size_t)n * LL;

    // resident Q B-frags: B[k=c][ncol=m] -> Qt[m0+mst*16+mc][32s+8q+j]
    short8 qf[2][4];
    #pragma unroll
    for (int mst = 0; mst < 2; ++mst)
        #pragma unroll
        for (int s = 0; s < 4; ++s)
            qf[mst][s] = *(const short8*)(const void*)(
                Qn + ((size_t)(m0 + mst * 16 + mc)) * CH + 32 * s + quad * 8);

    floatx4 acc[2][2];  // [ct][mst]
    #pragma unroll
    for (int ct = 0; ct < 2; ++ct)
        #pragma unroll
        for (int mst = 0; mst < 2; ++mst)
            acc[ct][mst] = (floatx4){0.f, 0.f, 0.f, 0.f};

    for (int lb = 0; lb < LL; lb += 64) {
        // ---- phase 1: S rows [lrow, lrow+16) x 32 cols, -> P in LDS ----
        const int lrow = lb + 16 * wave;
        short8 kfr[4];
        #pragma unroll
        for (int s = 0; s < 4; ++s)
            kfr[s] = *(const short8*)(const void*)(
                Kn + ((size_t)(lrow + mc)) * CH + 32 * s + quad * 8);
        float d[4];
        #pragma unroll
        for (int r = 0; r < 4; ++r) d[r] = Dn[lrow + quad * 4 + r];

        #pragma unroll
        for (int mst = 0; mst < 2; ++mst) {
            floatx4 sa = {0.f, 0.f, 0.f, 0.f};
            #pragma unroll
            for (int s = 0; s < 4; ++s)
                sa = __builtin_amdgcn_mfma_f32_16x16x32_bf16(kfr[s], qf[mst][s], sa, 0, 0, 0);
            short4b pv;
            #pragma unroll
            for (int r = 0; r < 4; ++r) pv[r] = f2bf(__expf(sa[r]) * d[r]);
            // C-layout (row=4q+r, col=mc) -> LDS [m][l]: 4 consecutive l = 8B
            *(short4b*)(void*)&P[mst * 16 + mc][16 * wave + quad * 4] = pv;
        }
        __syncthreads();

        // ---- phase 2: acc += V[cw..cw+32][lb..lb+64] * P ----
        short8 vf[2][2];
        #pragma unroll
        for (int ct = 0; ct < 2; ++ct)
            #pragma unroll
            for (int t = 0; t < 2; ++t)
                vf[ct][t] = *(const short8*)(const void*)(
                    Vb + ((size_t)(cw + ct * 16 + mc)) * LL + lb + 32 * t + quad * 8);

        #pragma unroll
        for (int mst = 0; mst < 2; ++mst) {
            const short8 p0 = *(const short8*)(const void*)&P[mst * 16 + mc][quad * 8];
            const short8 p1 = *(const short8*)(const void*)&P[mst * 16 + mc][32 + quad * 8];
            #pragma unroll
            for (int ct = 0; ct < 2; ++ct) {
                acc[ct][mst] = __builtin_amdgcn_mfma_f32_16x16x32_bf16(vf[ct][0], p0, acc[ct][mst], 0, 0, 0);
                acc[ct][mst] = __builtin_amdgcn_mfma_f32_16x16x32_bf16(vf[ct][1], p1, acc[ct][mst], 0, 0, 0);
            }
        }
        __syncthreads();
    }

    // ---- epilogue: out = x + O ----
    #pragma unroll
    for (int ct = 0; ct < 2; ++ct)
        #pragma unroll
        for (int mst = 0; mst < 2; ++mst)
            #pragma unroll
            for (int r = 0; r < 4; ++r) {
                const int c = cw + ct * 16 + quad * 4 + r;   // C-layout row
                const int m = m0 + mst * 16 + mc;            // C-layout col
                const size_t idx = ((size_t)n * CH + c) * LL + m;
                out[idx] = x[idx] + acc[ct][mst][r];
            }
}

// ---------------------------------------------------------------------------
extern "C" void kernel_launch(void* const* d_in, const int* in_sizes, int n_in,
                              void* d_out, int out_size, void* d_ws, size_t ws_size,
                              hipStream_t stream) {
    (void)in_sizes; (void)n_in; (void)out_size; (void)ws_size;
    const float* x  = (const float*)d_in[0];
    const float* Wq = (const float*)d_in[1];
    const float* bq = (const float*)d_in[2];
    const float* Wk = (const float*)d_in[3];
    const float* bk = (const float*)d_in[4];
    const float* Wv = (const float*)d_in[5];
    const float* bv = (const float*)d_in[6];
    float* out = (float*)d_out;

    char* ws = (char*)d_ws;
    // ws layout: Qt 4MB | Kt 4MB | Vn 4MB | Drcp 16KB  (total ~12.6 MB)
    short* Qt = (short*)(ws);
    short* Kt = (short*)(ws + 4194304);
    short* Vn = (short*)(ws + 8388608);
    float* Dr = (float*)(ws + 12582912);

    proj_kernel<<<512, 256, 0, stream>>>(x, Wq, bq, Wk, bk, Wv, bv, Qt, Kt, Vn);
    rowsum_kernel<<<256, 256, 0, stream>>>(Qt, Kt, Dr);
    attn_out_kernel<<<512, 256, 0, stream>>>(Qt, Kt, Vn, Dr, x, out);
}

// Round 4
// 344.954 us; speedup vs baseline: 1.1707x; 1.1707x over previous
//
#include <hip/hip_runtime.h>
#include <hip/hip_bf16.h>
#include <stdint.h>

// Problem constants (N,C,H,W = 4,128,64,64)
#define NB 4
#define CH 128
#define LL 4096   // H*W

typedef __attribute__((ext_vector_type(8))) short short8;   // 8 bf16 (4 VGPRs) MFMA A/B frag
typedef __attribute__((ext_vector_type(4))) short short4b;  // 4 bf16 (8B)
typedef __attribute__((ext_vector_type(4))) float floatx4;  // MFMA C/D frag

static __device__ __forceinline__ short f2bf(float f) {
    // round-to-nearest-even fp32 -> bf16
    uint32_t u = __float_as_uint(f);
    u += 0x7fffu + ((u >> 16) & 1u);
    return (short)(u >> 16);
}

// ---------------------------------------------------------------------------
// Kernel 1: QKV projection. Writes Qt[n][l][c], Kt[n][l][c] (K pre-scaled by
// 1/sqrt(C)), Vn[n][c][l], all bf16.
// grid = NB * 16(o-blocks of 8) * 16(l-chunks of 256) = 1024 blocks
//   -> 4 blocks/CU = 16 waves/CU (50% occ; was 25% with o-blocks of 16).
// c-loop unrolled x4 so W scalar loads batch into s_load_dwordx4.
// ---------------------------------------------------------------------------
__global__ __launch_bounds__(256) void proj_kernel(
    const float* __restrict__ x,
    const float* __restrict__ Wq, const float* __restrict__ bq,
    const float* __restrict__ Wk, const float* __restrict__ bk,
    const float* __restrict__ Wv, const float* __restrict__ bv,
    short* __restrict__ Qt, short* __restrict__ Kt, short* __restrict__ Vn)
{
    const int b   = blockIdx.x;
    const int n   = b >> 8;            // 256 blocks per n
    const int rem = b & 255;
    const int o0  = (rem >> 4) * 8;    // 16 o-blocks of 8 outputs
    const int l   = ((rem & 15) << 8) + threadIdx.x;  // 16 l-chunks of 256

    const float* xp = x + ((size_t)n * CH) * LL + l;

    float aq[8], ak[8], av[8];
    #pragma unroll
    for (int u = 0; u < 8; ++u) {
        aq[u] = bq[o0 + u];
        ak[u] = bk[o0 + u];
        av[u] = bv[o0 + u];
    }

    #pragma unroll 4
    for (int c = 0; c < CH; ++c) {
        const float xv = xp[(size_t)c * LL];   // coalesced across lanes
        #pragma unroll
        for (int u = 0; u < 8; ++u) {
            // W indices wave-uniform -> s_load (x4-batched by the unroll)
            aq[u] += Wq[(o0 + u) * CH + c] * xv;
            ak[u] += Wk[(o0 + u) * CH + c] * xv;
            av[u] += Wv[(o0 + u) * CH + c] * xv;
        }
    }

    const float scale = 0.08838834764831845f;  // 1/sqrt(128), folded into K
    short8 q0, k0;
    #pragma unroll
    for (int u = 0; u < 8; ++u) {
        q0[u] = f2bf(aq[u]);
        k0[u] = f2bf(ak[u] * scale);
    }
    *(short8*)(void*)(Qt + ((size_t)n * LL + l) * CH + o0) = q0;
    *(short8*)(void*)(Kt + ((size_t)n * LL + l) * CH + o0) = k0;
    #pragma unroll
    for (int u = 0; u < 8; ++u)   // coalesced across lanes (l contiguous)
        Vn[((size_t)n * CH + o0 + u) * LL + l] = f2bf(av[u]);
}

// ---------------------------------------------------------------------------
// Kernel 2: softmax denominators. Drcp[l] = 1 / sum_m exp(S[l,m]).
// grid = NB * 256 (16 rows per block) = 1024 blocks -> 4 blocks/CU (50% occ;
// was 1 block/CU). All 4 waves share the 16 K rows (A-frags); each wave
// sweeps 1/4 of the m-tiles with TWO independent MFMA chains for ILP;
// cross-wave reduce via LDS at the end.
// ---------------------------------------------------------------------------
__global__ __launch_bounds__(256) void rowsum_kernel(
    const short* __restrict__ Qt, const short* __restrict__ Kt,
    float* __restrict__ Drcp)
{
    const int b    = blockIdx.x;
    const int n    = b >> 8;
    const int l0   = (b & 255) << 4;
    const int wave = threadIdx.x >> 6;
    const int lane = threadIdx.x & 63;
    const int quad = lane >> 4;
    const int mc   = lane & 15;

    __shared__ float R[4][16];

    // A-frag: A[m=mc][k=32s+8q+j] = K[l0+mc][c]  (same rows for all 4 waves)
    const short* kb = Kt + ((size_t)n * LL + l0 + mc) * CH + quad * 8;
    short8 kf[4];
    #pragma unroll
    for (int s = 0; s < 4; ++s) kf[s] = *(const short8*)(const void*)(kb + 32 * s);

    const short* Qn = Qt + (size_t)n * LL * CH;
    float rs[4] = {0.f, 0.f, 0.f, 0.f};

    // wave handles m-tiles t = wave + 4*i, i = 0..63; pairs for 2 ILP chains
    for (int ii = 0; ii < 64; ii += 2) {
        const short* qa = Qn + ((size_t)(16 * wave + 64 * ii + mc)) * CH + quad * 8;
        const short* qc = qa + (size_t)64 * CH;   // tile ii+1 (m += 64)
        floatx4 a0 = {0.f, 0.f, 0.f, 0.f};
        floatx4 a1 = {0.f, 0.f, 0.f, 0.f};
        #pragma unroll
        for (int s = 0; s < 4; ++s) {
            a0 = __builtin_amdgcn_mfma_f32_16x16x32_bf16(
                kf[s], *(const short8*)(const void*)(qa + 32 * s), a0, 0, 0, 0);
            a1 = __builtin_amdgcn_mfma_f32_16x16x32_bf16(
                kf[s], *(const short8*)(const void*)(qc + 32 * s), a1, 0, 0, 0);
        }
        #pragma unroll
        for (int r = 0; r < 4; ++r) rs[r] += __expf(a0[r]) + __expf(a1[r]);
    }

    // reduce over the 16 column-lanes (C-layout: col = lane&15)
    #pragma unroll
    for (int r = 0; r < 4; ++r) {
        float v = rs[r];
        v += __shfl_xor(v, 1);
        v += __shfl_xor(v, 2);
        v += __shfl_xor(v, 4);
        v += __shfl_xor(v, 8);
        rs[r] = v;
    }
    if (mc == 0) {
        #pragma unroll
        for (int r = 0; r < 4; ++r)     // C-layout row = quad*4 + r
            R[wave][quad * 4 + r] = rs[r];
    }
    __syncthreads();
    if (threadIdx.x < 16) {
        const float t = R[0][threadIdx.x] + R[1][threadIdx.x] +
                        R[2][threadIdx.x] + R[3][threadIdx.x];
        Drcp[(size_t)n * LL + l0 + threadIdx.x] = 1.0f / t;
    }
}

// ---------------------------------------------------------------------------
// Kernel 3: O[c,m] = sum_l V[c,l]*exp(S[l,m])*Drcp[l];  out = x + O.
// grid = NB*128 = 512 blocks x 512 threads (8 waves) -> 2 blocks/CU =
// 16 waves/CU (50% occ; was 22.7%). l-step = 256: 16 steps, 32 barriers
// (was 128), 32 MFMAs/wave per barrier-pair (was 16).
// Phase1: wave w computes S stripes (rows lb+16*(w+8s), s=0,1) x 32 cols,
// exp*rcpD -> bf16 P in LDS [m][l] (B-operand layout, stride 264 = 16B-
// aligned, banks shift 4/row -> <=2-way conflicts, free per m136).
// Phase2: wave w owns 16 channels: V(A) x P(B) over 8 l-chunks of 32.
// ---------------------------------------------------------------------------
__global__ __launch_bounds__(512, 4) void attn_out_kernel(
    const short* __restrict__ Qt, const short* __restrict__ Kt,
    const short* __restrict__ Vn, const float* __restrict__ Drcp,
    const float* __restrict__ x, float* __restrict__ out)
{
    const int b    = blockIdx.x;
    const int n    = b >> 7;            // 128 m-blocks per n
    const int m0   = (b & 127) << 5;
    const int wave = threadIdx.x >> 6;  // 0..7
    const int lane = threadIdx.x & 63;
    const int quad = lane >> 4;
    const int mc   = lane & 15;
    const int cw   = wave * 16;         // wave's 16 output channels

    __shared__ short P[32][264];        // [m][l] bf16, 256 l + 8 pad (16.9 KB)

    const short* Qn = Qt + (size_t)n * LL * CH;
    const short* Kn = Kt + (size_t)n * LL * CH;
    const short* Vb = Vn + (size_t)n * CH * LL;
    const float* Dn = Drcp + (size_t)n * LL;

    // resident Q B-frags: B[k=c][col=m] = Qt[m0+mst*16+mc][32s+8q+j]
    short8 qf[2][4];
    #pragma unroll
    for (int mst = 0; mst < 2; ++mst)
        #pragma unroll
        for (int s = 0; s < 4; ++s)
            qf[mst][s] = *(const short8*)(const void*)(
                Qn + ((size_t)(m0 + mst * 16 + mc)) * CH + 32 * s + quad * 8);

    floatx4 acc[2];
    acc[0] = (floatx4){0.f, 0.f, 0.f, 0.f};
    acc[1] = (floatx4){0.f, 0.f, 0.f, 0.f};

    for (int lb = 0; lb < LL; lb += 256) {
        // ---- phase 1: 16 stripes of 16 S-rows x 32 cols -> P in LDS ----
        #pragma unroll
        for (int s = 0; s < 2; ++s) {
            const int stripe = wave + 8 * s;          // 0..15
            const int lrow   = lb + 16 * stripe;
            short8 kfr[4];
            #pragma unroll
            for (int t = 0; t < 4; ++t)
                kfr[t] = *(const short8*)(const void*)(
                    Kn + ((size_t)(lrow + mc)) * CH + 32 * t + quad * 8);
            float d[4];
            #pragma unroll
            for (int r = 0; r < 4; ++r) d[r] = Dn[lrow + quad * 4 + r];

            #pragma unroll
            for (int mst = 0; mst < 2; ++mst) {
                floatx4 sa = {0.f, 0.f, 0.f, 0.f};
                #pragma unroll
                for (int t = 0; t < 4; ++t)
                    sa = __builtin_amdgcn_mfma_f32_16x16x32_bf16(
                        kfr[t], qf[mst][t], sa, 0, 0, 0);
                short4b pv;
                #pragma unroll
                for (int r = 0; r < 4; ++r) pv[r] = f2bf(__expf(sa[r]) * d[r]);
                // C-layout (row=l=4q+r, col=m=mc) -> P[m][l], 8B store
                *(short4b*)(void*)&P[mst * 16 + mc][16 * stripe + quad * 4] = pv;
            }
        }
        __syncthreads();

        // ---- phase 2: acc += V[cw..cw+16][lb..lb+256] * P ----
        #pragma unroll
        for (int c8 = 0; c8 < 8; ++c8) {
            // A-frag: A[m=c(mc)][k=32c8+8q+j]
            const short8 vf = *(const short8*)(const void*)(
                Vb + ((size_t)(cw + mc)) * LL + lb + 32 * c8 + quad * 8);
            // B-frag: B[k=8q+j][col=m(mc)]
            const short8 p0 = *(const short8*)(const void*)&P[mc][32 * c8 + quad * 8];
            const short8 p1 = *(const short8*)(const void*)&P[16 + mc][32 * c8 + quad * 8];
            acc[0] = __builtin_amdgcn_mfma_f32_16x16x32_bf16(vf, p0, acc[0], 0, 0, 0);
            acc[1] = __builtin_amdgcn_mfma_f32_16x16x32_bf16(vf, p1, acc[1], 0, 0, 0);
        }
        __syncthreads();
    }

    // ---- epilogue: out = x + O ----
    #pragma unroll
    for (int mst = 0; mst < 2; ++mst)
        #pragma unroll
        for (int r = 0; r < 4; ++r) {
            const int c = cw + quad * 4 + r;     // C-layout row
            const int m = m0 + mst * 16 + mc;    // C-layout col
            const size_t idx = ((size_t)n * CH + c) * LL + m;
            out[idx] = x[idx] + acc[mst][r];
        }
}

// ---------------------------------------------------------------------------
extern "C" void kernel_launch(void* const* d_in, const int* in_sizes, int n_in,
                              void* d_out, int out_size, void* d_ws, size_t ws_size,
                              hipStream_t stream) {
    (void)in_sizes; (void)n_in; (void)out_size; (void)ws_size;
    const float* x  = (const float*)d_in[0];
    const float* Wq = (const float*)d_in[1];
    const float* bq = (const float*)d_in[2];
    const float* Wk = (const float*)d_in[3];
    const float* bk = (const float*)d_in[4];
    const float* Wv = (const float*)d_in[5];
    const float* bv = (const float*)d_in[6];
    float* out = (float*)d_out;

    char* ws = (char*)d_ws;
    // ws layout: Qt 4MB | Kt 4MB | Vn 4MB | Drcp 16KB  (total ~12.6 MB)
    short* Qt = (short*)(ws);
    short* Kt = (short*)(ws + 4194304);
    short* Vn = (short*)(ws + 8388608);
    float* Dr = (float*)(ws + 12582912);

    proj_kernel<<<1024, 256, 0, stream>>>(x, Wq, bq, Wk, bk, Wv, bv, Qt, Kt, Vn);
    rowsum_kernel<<<1024, 256, 0, stream>>>(Qt, Kt, Dr);
    attn_out_kernel<<<512, 512, 0, stream>>>(Qt, Kt, Vn, Dr, x, out);
}

// Round 6
// 234.460 us; speedup vs baseline: 1.7225x; 1.4713x over previous
//
#include <hip/hip_runtime.h>
#include <hip/hip_bf16.h>
#include <stdint.h>

// Problem constants (N,C,H,W = 4,128,64,64)
#define NB 4
#define CH 128
#define LL 4096   // H*W

typedef __attribute__((ext_vector_type(8))) short short8;   // 8 bf16 MFMA A/B frag
typedef __attribute__((ext_vector_type(4))) short short4b;  // 4 bf16 (8B)
typedef __attribute__((ext_vector_type(4))) float floatx4;  // 16x16 C/D frag
typedef __attribute__((ext_vector_type(16))) float floatx16; // 32x32 C/D frag

static __device__ __forceinline__ short f2bf(float f) {
    uint32_t u = __float_as_uint(f);
    u += 0x7fffu + ((u >> 16) & 1u);
    return (short)(u >> 16);
}

// ---------------------------------------------------------------------------
// Kernel 1: QKV projection. Writes Qt[n][l][c], Kt[n][l][c] (K pre-scaled
// 1/sqrt(C)), Vn[n][c][l], bf16.
// ---------------------------------------------------------------------------
__global__ __launch_bounds__(256) void proj_kernel(
    const float* __restrict__ x,
    const float* __restrict__ Wq, const float* __restrict__ bq,
    const float* __restrict__ Wk, const float* __restrict__ bk,
    const float* __restrict__ Wv, const float* __restrict__ bv,
    short* __restrict__ Qt, short* __restrict__ Kt, short* __restrict__ Vn)
{
    const int b   = blockIdx.x;
    const int n   = b >> 8;
    const int rem = b & 255;
    const int o0  = (rem >> 4) * 8;
    const int l   = ((rem & 15) << 8) + threadIdx.x;

    const float* xp = x + ((size_t)n * CH) * LL + l;

    float aq[8], ak[8], av[8];
    #pragma unroll
    for (int u = 0; u < 8; ++u) {
        aq[u] = bq[o0 + u];
        ak[u] = bk[o0 + u];
        av[u] = bv[o0 + u];
    }

    #pragma unroll 4
    for (int c = 0; c < CH; ++c) {
        const float xv = xp[(size_t)c * LL];
        #pragma unroll
        for (int u = 0; u < 8; ++u) {
            aq[u] += Wq[(o0 + u) * CH + c] * xv;
            ak[u] += Wk[(o0 + u) * CH + c] * xv;
            av[u] += Wv[(o0 + u) * CH + c] * xv;
        }
    }

    const float scale = 0.08838834764831845f;  // 1/sqrt(128), folded into K
    short8 q0, k0;
    #pragma unroll
    for (int u = 0; u < 8; ++u) {
        q0[u] = f2bf(aq[u]);
        k0[u] = f2bf(ak[u] * scale);
    }
    *(short8*)(void*)(Qt + ((size_t)n * LL + l) * CH + o0) = q0;
    *(short8*)(void*)(Kt + ((size_t)n * LL + l) * CH + o0) = k0;
    #pragma unroll
    for (int u = 0; u < 8; ++u)
        Vn[((size_t)n * CH + o0 + u) * LL + l] = f2bf(av[u]);
}

// ---------------------------------------------------------------------------
// Kernel 2: partial softmax denominators. Block = (n, l-tile 64, m-quarter).
// grid = 4*64*4 = 1024 blocks, 256 thr (4 blocks/CU). K-tile staged once,
// A-frags held in regs whole kernel. Q-tiles (64 m) staged per step with
// register prefetch; all LDS frag reads conflict-free (row stride 272B).
// ---------------------------------------------------------------------------
__global__ __launch_bounds__(256, 4) void rowsum_kernel(
    const short* __restrict__ Qt, const short* __restrict__ Kt,
    float* __restrict__ Dpart)
{
    const int b    = blockIdx.x;
    const int n    = b >> 8;
    const int rem  = b & 255;
    const int lt   = rem >> 2;           // 0..63
    const int mq   = rem & 3;            // 0..3
    const int l0   = lt * 64;
    const int tid  = threadIdx.x;
    const int wave = tid >> 6;
    const int lane = tid & 63;
    const int quad = lane >> 4;
    const int mc   = lane & 15;

    __shared__ short Kbuf[64][136];      // [l][c], +8 pad (row 272B)
    __shared__ short Qbuf[64][136];      // [m][c], +8 pad

    const short* Kn = Kt + ((size_t)n * LL + l0) * CH;
    const short* Qn = Qt + ((size_t)n * LL + mq * 1024) * CH;

    // stage K tile [64][128] once (coalesced)
    {
        const int row0 = tid >> 4, ch = tid & 15;
        #pragma unroll
        for (int i = 0; i < 4; ++i)
            *(short8*)(void*)&Kbuf[i * 16 + row0][ch * 8] =
                *(const short8*)(const void*)(Kn + (size_t)(i * 16 + row0) * CH + ch * 8);
    }
    // preload first Q tile into regs
    short8 qreg[4];
    {
        const int row0 = tid >> 4, ch = tid & 15;
        #pragma unroll
        for (int i = 0; i < 4; ++i)
            qreg[i] = *(const short8*)(const void*)(Qn + (size_t)(i * 16 + row0) * CH + ch * 8);
    }
    __syncthreads();

    // K A-frags, resident for the whole kernel: A[l=16w+mc][k=32s+8q+j]
    short8 kfr[4];
    #pragma unroll
    for (int s = 0; s < 4; ++s)
        kfr[s] = *(const short8*)(const void*)&Kbuf[16 * wave + mc][32 * s + quad * 8];

    float rs[4] = {0.f, 0.f, 0.f, 0.f};

    for (int step = 0; step < 16; ++step) {
        const int row0 = tid >> 4, ch = tid & 15;
        #pragma unroll
        for (int i = 0; i < 4; ++i)
            *(short8*)(void*)&Qbuf[i * 16 + row0][ch * 8] = qreg[i];
        if (step < 15) {
            const short* Qs = Qn + (size_t)(step + 1) * 64 * CH;
            #pragma unroll
            for (int i = 0; i < 4; ++i)
                qreg[i] = *(const short8*)(const void*)(Qs + (size_t)(i * 16 + row0) * CH + ch * 8);
        }
        __syncthreads();

        #pragma unroll
        for (int mt = 0; mt < 4; ++mt) {
            floatx4 acc = {0.f, 0.f, 0.f, 0.f};
            #pragma unroll
            for (int s = 0; s < 4; ++s)
                acc = __builtin_amdgcn_mfma_f32_16x16x32_bf16(
                    kfr[s],
                    *(const short8*)(const void*)&Qbuf[16 * mt + mc][32 * s + quad * 8],
                    acc, 0, 0, 0);
            #pragma unroll
            for (int r = 0; r < 4; ++r) rs[r] += __expf(acc[r]);
        }
        __syncthreads();
    }

    // reduce over the 16 column-lanes (C-layout col = lane&15)
    #pragma unroll
    for (int r = 0; r < 4; ++r) {
        float v = rs[r];
        v += __shfl_xor(v, 1);
        v += __shfl_xor(v, 2);
        v += __shfl_xor(v, 4);
        v += __shfl_xor(v, 8);
        rs[r] = v;
    }
    if (mc == 0) {
        #pragma unroll
        for (int r = 0; r < 4; ++r)   // l = l0 + 16*wave + quad*4 + r
            Dpart[(size_t)mq * (NB * LL) + (size_t)n * LL + l0 + 16 * wave + quad * 4 + r] = rs[r];
    }
}

// ---------------------------------------------------------------------------
// Kernel 2b: combine partial denominators -> reciprocal.
// ---------------------------------------------------------------------------
__global__ __launch_bounds__(256) void dcombine_kernel(
    const float* __restrict__ Dpart, float* __restrict__ Drcp)
{
    const int g = blockIdx.x * 256 + threadIdx.x;   // 0..16383
    const float s = Dpart[g] + Dpart[16384 + g] + Dpart[32768 + g] + Dpart[49152 + g];
    Drcp[g] = 1.0f / s;
}

// ---------------------------------------------------------------------------
// Kernel 3: O[c,m] = sum_l V[c,l]*exp(S[l,m])*Drcp[l];  out = x + O.
// grid = 4*64 = 256 blocks x 512 thr (1 block/CU). m-block 64, BK=128.
// Per step: stage K [128 l][128 c] -> LDS (coalesced, reg-prefetched);
// phase A (16x16 MFMA, verified layouts): each wave one 16-l stripe x 64 m,
// exp * Drcp -> bf16 P[64 m][128 l] in LDS; phase B (32x32x16 MFMA): wave
// owns 32c x 32m, k=128 per step; V A-frags direct from global (lines fully
// consumed via L1). All LDS rows stride 272B => conflict-free b128.
// ---------------------------------------------------------------------------
__global__ __launch_bounds__(512, 2) void attn_out_kernel(
    const short* __restrict__ Qt, const short* __restrict__ Kt,
    const short* __restrict__ Vn, const float* __restrict__ Drcp,
    const float* __restrict__ x, float* __restrict__ out)
{
    const int b    = blockIdx.x;
    const int n    = b >> 6;
    const int m0   = (b & 63) << 6;
    const int tid  = threadIdx.x;
    const int wave = tid >> 6;        // 0..7
    const int lane = tid & 63;
    const int quad = lane >> 4;
    const int mc   = lane & 15;
    const int l32  = lane & 31;
    const int h    = lane >> 5;

    __shared__ short Kbuf[128][136];  // [l][c] +8 pad (34.8 KB)
    __shared__ short P[64][136];      // [m][l] +8 pad (17.4 KB)

    const short* Qn = Qt + (size_t)n * LL * CH;
    const short* Kn = Kt + (size_t)n * LL * CH;
    const short* Vb = Vn + (size_t)n * CH * LL;
    const float* Dn = Drcp + (size_t)n * LL;

    // resident Q B-frags (16x16): B[k=c][col=m] = Qt[m0+16mst+mc][32s+8q+j]
    short8 qf[4][4];
    #pragma unroll
    for (int mst = 0; mst < 4; ++mst)
        #pragma unroll
        for (int s = 0; s < 4; ++s)
            qf[mst][s] = *(const short8*)(const void*)(
                Qn + (size_t)(m0 + 16 * mst + mc) * CH + 32 * s + quad * 8);

    // preload K tile 0 (coalesced: wave covers 4 contiguous 256B rows)
    const int srow = tid >> 4, sch = tid & 15;
    short8 kreg[4];
    #pragma unroll
    for (int i = 0; i < 4; ++i)
        kreg[i] = *(const short8*)(const void*)(
            Kn + (size_t)(i * 32 + srow) * CH + sch * 8);

    const int ct = wave & 3;          // c-tile (32 channels)
    const int mh = wave >> 2;         // m-half (32 cols)

    floatx16 acc;
    #pragma unroll
    for (int r = 0; r < 16; ++r) acc[r] = 0.f;

    for (int step = 0; step < 32; ++step) {
        const int lb = step * 128;

        // ---- stage K tile, prefetch next ----
        #pragma unroll
        for (int i = 0; i < 4; ++i)
            *(short8*)(void*)&Kbuf[i * 32 + srow][sch * 8] = kreg[i];
        if (step < 31) {
            const short* Ks = Kn + (size_t)(lb + 128) * CH;
            #pragma unroll
            for (int i = 0; i < 4; ++i)
                kreg[i] = *(const short8*)(const void*)(
                    Ks + (size_t)(i * 32 + srow) * CH + sch * 8);
        }
        __syncthreads();   // B1: Kbuf visible

        // ---- phase A: S stripe [16 l] x [64 m] -> P ----
        {
            short8 kfr[4];
            #pragma unroll
            for (int s = 0; s < 4; ++s)
                kfr[s] = *(const short8*)(const void*)&Kbuf[16 * wave + mc][32 * s + quad * 8];
            const floatx4 d = *(const floatx4*)(const void*)(Dn + lb + 16 * wave + quad * 4);
            #pragma unroll
            for (int mst = 0; mst < 4; ++mst) {
                floatx4 sa = {0.f, 0.f, 0.f, 0.f};
                #pragma unroll
                for (int s = 0; s < 4; ++s)
                    sa = __builtin_amdgcn_mfma_f32_16x16x32_bf16(kfr[s], qf[mst][s], sa, 0, 0, 0);
                short4b pv;
                #pragma unroll
                for (int r = 0; r < 4; ++r) pv[r] = f2bf(__expf(sa[r]) * d[r]);
                // C-layout (row=l=4q+r, col=m=mc) -> P[m][l-local]
                *(short4b*)(void*)&P[16 * mst + mc][16 * wave + quad * 4] = pv;
            }
        }
        __syncthreads();   // B2: P visible

        // ---- phase B: acc(32c x 32m) += V[.,lb..lb+128] * P ----
        #pragma unroll
        for (int kc = 0; kc < 8; ++kc) {
            // A-frag 32x32x16: A[row=c=l32][k=8h+j] = V[32ct+l32][lb+16kc+8h+j]
            const short8 vf = *(const short8*)(const void*)(
                Vb + (size_t)(32 * ct + l32) * LL + lb + 16 * kc + 8 * h);
            // B-frag 32x32x16: B[k=8h+j][col=m=l32] = P[32mh+l32][16kc+8h+j]
            const short8 pf = *(const short8*)(const void*)&P[32 * mh + l32][16 * kc + 8 * h];
            acc = __builtin_amdgcn_mfma_f32_32x32x16_bf16(vf, pf, acc, 0, 0, 0);
        }
        __syncthreads();   // B3: P/Kbuf reads done before next overwrite
    }

    // ---- epilogue: out = x + O (32x32 C-layout) ----
    #pragma unroll
    for (int r = 0; r < 16; ++r) {
        const int c = 32 * ct + (r & 3) + 8 * (r >> 2) + 4 * h;
        const int m = m0 + 32 * mh + l32;
        const size_t idx = ((size_t)n * CH + c) * LL + m;
        out[idx] = x[idx] + acc[r];
    }
}

// ---------------------------------------------------------------------------
extern "C" void kernel_launch(void* const* d_in, const int* in_sizes, int n_in,
                              void* d_out, int out_size, void* d_ws, size_t ws_size,
                              hipStream_t stream) {
    (void)in_sizes; (void)n_in; (void)out_size; (void)ws_size;
    const float* x  = (const float*)d_in[0];
    const float* Wq = (const float*)d_in[1];
    const float* bq = (const float*)d_in[2];
    const float* Wk = (const float*)d_in[3];
    const float* bk = (const float*)d_in[4];
    const float* Wv = (const float*)d_in[5];
    const float* bv = (const float*)d_in[6];
    float* out = (float*)d_out;

    char* ws = (char*)d_ws;
    // ws: Qt 4MB | Kt 4MB | Vn 4MB | Dpart 256KB | Drcp 64KB  (~12.9 MB)
    short* Qt = (short*)(ws);
    short* Kt = (short*)(ws + 4194304);
    short* Vn = (short*)(ws + 8388608);
    float* Dp = (float*)(ws + 12582912);
    float* Dr = (float*)(ws + 12582912 + 262144);

    proj_kernel<<<1024, 256, 0, stream>>>(x, Wq, bq, Wk, bk, Wv, bv, Qt, Kt, Vn);
    rowsum_kernel<<<1024, 256, 0, stream>>>(Qt, Kt, Dp);
    dcombine_kernel<<<64, 256, 0, stream>>>(Dp, Dr);
    attn_out_kernel<<<256, 512, 0, stream>>>(Qt, Kt, Vn, Dr, x, out);
}

// Round 7
// 205.959 us; speedup vs baseline: 1.9608x; 1.1384x over previous
//
#include <hip/hip_runtime.h>
#include <hip/hip_bf16.h>
#include <stdint.h>

// Problem constants (N,C,H,W = 4,128,64,64)
#define NB 4
#define CH 128
#define LL 4096   // H*W

typedef __attribute__((ext_vector_type(8))) short short8;   // 8 bf16 MFMA A/B frag
typedef __attribute__((ext_vector_type(4))) short short4b;  // 4 bf16 (8B)
typedef __attribute__((ext_vector_type(4))) float floatx4;  // 16x16 C/D frag
typedef __attribute__((ext_vector_type(16))) float floatx16; // 32x32 C/D frag

static __device__ __forceinline__ short f2bf(float f) {
    uint32_t u = __float_as_uint(f);
    u += 0x7fffu + ((u >> 16) & 1u);
    return (short)(u >> 16);
}

// ---------------------------------------------------------------------------
// Kernel 1: QKV projection. Qt[n][l][c], Kt[n][l][c] (K pre-scaled 1/sqrt(C)),
// and V in PANEL layout Vp[n][l>>4][c][l&15] so attn phase-B A-frag reads are
// fully coalesced 1KB instructions (fixes the 32-line V scatter seen in R6).
// ---------------------------------------------------------------------------
__global__ __launch_bounds__(256) void proj_kernel(
    const float* __restrict__ x,
    const float* __restrict__ Wq, const float* __restrict__ bq,
    const float* __restrict__ Wk, const float* __restrict__ bk,
    const float* __restrict__ Wv, const float* __restrict__ bv,
    short* __restrict__ Qt, short* __restrict__ Kt, short* __restrict__ Vp)
{
    const int b   = blockIdx.x;
    const int n   = b >> 8;
    const int rem = b & 255;
    const int o0  = (rem >> 4) * 8;
    const int l   = ((rem & 15) << 8) + threadIdx.x;

    const float* xp = x + ((size_t)n * CH) * LL + l;

    float aq[8], ak[8], av[8];
    #pragma unroll
    for (int u = 0; u < 8; ++u) {
        aq[u] = bq[o0 + u];
        ak[u] = bk[o0 + u];
        av[u] = bv[o0 + u];
    }

    #pragma unroll 4
    for (int c = 0; c < CH; ++c) {
        const float xv = xp[(size_t)c * LL];
        #pragma unroll
        for (int u = 0; u < 8; ++u) {
            aq[u] += Wq[(o0 + u) * CH + c] * xv;
            ak[u] += Wk[(o0 + u) * CH + c] * xv;
            av[u] += Wv[(o0 + u) * CH + c] * xv;
        }
    }

    const float scale = 0.08838834764831845f;  // 1/sqrt(128), folded into K
    short8 q0, k0;
    #pragma unroll
    for (int u = 0; u < 8; ++u) {
        q0[u] = f2bf(aq[u]);
        k0[u] = f2bf(ak[u] * scale);
    }
    *(short8*)(void*)(Qt + ((size_t)n * LL + l) * CH + o0) = q0;
    *(short8*)(void*)(Kt + ((size_t)n * LL + l) * CH + o0) = k0;
    // panel write: 16 consecutive lanes (same l>>4) write 32B contiguous
    short* vpan = Vp + ((size_t)n * 256 + (l >> 4)) * 2048 + (l & 15);
    #pragma unroll
    for (int u = 0; u < 8; ++u)
        vpan[(o0 + u) * 16] = f2bf(av[u]);
}

// ---------------------------------------------------------------------------
// Kernel 2: softmax denominators via S^T tiles. Block = (n, m-block 64,
// l-half). grid = 4*64*2 = 512 (2 blocks/CU). A = Q (resident regs, rows=m),
// B = K (staged LDS w/ reg prefetch, cols=l). C cols = l => per-lane partial
// rowsum; 2 quad-shuffles + atomicAdd into zeroed Dsum. K read redundancy 1.
// ---------------------------------------------------------------------------
__global__ __launch_bounds__(512, 2) void rowsum_kernel(
    const short* __restrict__ Qt, const short* __restrict__ Kt,
    float* __restrict__ Dsum)
{
    const int b    = blockIdx.x;
    const int n    = b >> 7;
    const int rem  = b & 127;
    const int m0   = (rem >> 1) << 6;
    const int lh   = rem & 1;
    const int tid  = threadIdx.x;
    const int wave = tid >> 6;
    const int lane = tid & 63;
    const int quad = lane >> 4;
    const int mc   = lane & 15;

    __shared__ short Kbuf[128][136];   // [l][c] +8 pad (34.8 KB)

    const short* Qn = Qt + (size_t)n * LL * CH;
    const short* Kn = Kt + (size_t)n * LL * CH + (size_t)lh * 2048 * CH;

    // resident Q A-frags: A[m=m0+16mst+mc][k=32s+8q+j]
    short8 qf[4][4];
    #pragma unroll
    for (int mst = 0; mst < 4; ++mst)
        #pragma unroll
        for (int s = 0; s < 4; ++s)
            qf[mst][s] = *(const short8*)(const void*)(
                Qn + (size_t)(m0 + 16 * mst + mc) * CH + 32 * s + quad * 8);

    const int srow = tid >> 4, sch = tid & 15;
    short8 kreg[4];
    #pragma unroll
    for (int i = 0; i < 4; ++i)
        kreg[i] = *(const short8*)(const void*)(
            Kn + (size_t)(i * 32 + srow) * CH + sch * 8);

    for (int step = 0; step < 16; ++step) {
        const int lb = step << 7;
        #pragma unroll
        for (int i = 0; i < 4; ++i)
            *(short8*)(void*)&Kbuf[i * 32 + srow][sch * 8] = kreg[i];
        if (step < 15) {
            const short* Ks = Kn + (size_t)(lb + 128) * CH;
            #pragma unroll
            for (int i = 0; i < 4; ++i)
                kreg[i] = *(const short8*)(const void*)(
                    Ks + (size_t)(i * 32 + srow) * CH + sch * 8);
        }
        __syncthreads();   // Kbuf visible

        // B-frags: B[k=32s+8q+j][col=l=16*wave+mc]
        short8 kfr[4];
        #pragma unroll
        for (int s = 0; s < 4; ++s)
            kfr[s] = *(const short8*)(const void*)&Kbuf[16 * wave + mc][32 * s + quad * 8];
        __syncthreads();   // all reads in regs -> next staging safe

        float rsum = 0.f;
        #pragma unroll
        for (int mst = 0; mst < 4; ++mst) {
            floatx4 a = {0.f, 0.f, 0.f, 0.f};
            #pragma unroll
            for (int s = 0; s < 4; ++s)
                a = __builtin_amdgcn_mfma_f32_16x16x32_bf16(qf[mst][s], kfr[s], a, 0, 0, 0);
            #pragma unroll
            for (int r = 0; r < 4; ++r) rsum += __expf(a[r]);
        }
        // sum the 4 quad-rows (m) for this lane's l-column
        rsum += __shfl_xor(rsum, 16);
        rsum += __shfl_xor(rsum, 32);
        if (lane < 16)
            atomicAdd(&Dsum[(size_t)n * LL + lh * 2048 + lb + 16 * wave + lane], rsum);
    }
}

// ---------------------------------------------------------------------------
// Kernel 2b: reciprocal.
// ---------------------------------------------------------------------------
__global__ __launch_bounds__(256) void rcp_kernel(
    const float* __restrict__ Dsum, float* __restrict__ Drcp)
{
    const int g = blockIdx.x * 256 + threadIdx.x;   // 0..16383
    Drcp[g] = 1.0f / Dsum[g];
}

// ---------------------------------------------------------------------------
// Kernel 3: O[c,m] = sum_l V[c,l]*exp(S[l,m])*Drcp[l];  out = x + O.
// grid 256 x 512thr, m-block 64, BK=128. Per step: stage K (coalesced, reg
// prefetch) -> phase A S-stripes -> P[64m][128l] LDS -> phase B V(panel,
// coalesced global) x P via 32x32x16 MFMA (layout verified R6). Phase B
// bulk-loads pf then barriers immediately so the MFMA chain overlaps the
// next step's staging.
// ---------------------------------------------------------------------------
__global__ __launch_bounds__(512, 2) void attn_out_kernel(
    const short* __restrict__ Qt, const short* __restrict__ Kt,
    const short* __restrict__ Vp, const float* __restrict__ Drcp,
    const float* __restrict__ x, float* __restrict__ out)
{
    const int b    = blockIdx.x;
    const int n    = b >> 6;
    const int m0   = (b & 63) << 6;
    const int tid  = threadIdx.x;
    const int wave = tid >> 6;        // 0..7
    const int lane = tid & 63;
    const int quad = lane >> 4;
    const int mc   = lane & 15;
    const int l32  = lane & 31;
    const int h    = lane >> 5;
    const int ct   = wave & 3;        // c-tile (32 channels)
    const int mh   = wave >> 2;       // m-half (32 cols)

    __shared__ short Kbuf[128][136];  // [l][c] +8 pad (34.8 KB)
    __shared__ short P[64][136];      // [m][l] +8 pad (17.4 KB)

    const short* Qn  = Qt + (size_t)n * LL * CH;
    const short* Kn  = Kt + (size_t)n * LL * CH;
    const short* Vpn = Vp + (size_t)n * 524288;
    const float* Dn  = Drcp + (size_t)n * LL;

    // resident Q B-frags: B[k=c][col=m]
    short8 qf[4][4];
    #pragma unroll
    for (int mst = 0; mst < 4; ++mst)
        #pragma unroll
        for (int s = 0; s < 4; ++s)
            qf[mst][s] = *(const short8*)(const void*)(
                Qn + (size_t)(m0 + 16 * mst + mc) * CH + 32 * s + quad * 8);

    const int srow = tid >> 4, sch = tid & 15;
    short8 kreg[4];
    #pragma unroll
    for (int i = 0; i < 4; ++i)
        kreg[i] = *(const short8*)(const void*)(
            Kn + (size_t)(i * 32 + srow) * CH + sch * 8);

    floatx16 acc;
    #pragma unroll
    for (int r = 0; r < 16; ++r) acc[r] = 0.f;

    for (int step = 0; step < 32; ++step) {
        const int lb = step << 7;

        // V A-frags for this step: fully coalesced panel loads (1KB/instr)
        short8 vf[8];
        #pragma unroll
        for (int kc = 0; kc < 8; ++kc)
            vf[kc] = *(const short8*)(const void*)(
                Vpn + (size_t)((lb >> 4) + kc) * 2048 + (32 * ct + l32) * 16 + 8 * h);

        // stage K tile, prefetch next
        #pragma unroll
        for (int i = 0; i < 4; ++i)
            *(short8*)(void*)&Kbuf[i * 32 + srow][sch * 8] = kreg[i];
        if (step < 31) {
            const short* Ks = Kn + (size_t)(lb + 128) * CH;
            #pragma unroll
            for (int i = 0; i < 4; ++i)
                kreg[i] = *(const short8*)(const void*)(
                    Ks + (size_t)(i * 32 + srow) * CH + sch * 8);
        }
        __syncthreads();   // B1: Kbuf visible

        // ---- phase A: S stripe [16 l] x [64 m] -> P ----
        {
            short8 kfr[4];
            #pragma unroll
            for (int s = 0; s < 4; ++s)
                kfr[s] = *(const short8*)(const void*)&Kbuf[16 * wave + mc][32 * s + quad * 8];
            const floatx4 d = *(const floatx4*)(const void*)(Dn + lb + 16 * wave + quad * 4);
            #pragma unroll
            for (int mst = 0; mst < 4; ++mst) {
                floatx4 sa = {0.f, 0.f, 0.f, 0.f};
                #pragma unroll
                for (int s = 0; s < 4; ++s)
                    sa = __builtin_amdgcn_mfma_f32_16x16x32_bf16(kfr[s], qf[mst][s], sa, 0, 0, 0);
                short4b pv;
                #pragma unroll
                for (int r = 0; r < 4; ++r) pv[r] = f2bf(__expf(sa[r]) * d[r]);
                *(short4b*)(void*)&P[16 * mst + mc][16 * wave + quad * 4] = pv;
            }
        }
        __syncthreads();   // B2: P visible

        // ---- phase B: bulk-load pf, release LDS, then MFMA ----
        short8 pf[8];
        #pragma unroll
        for (int kc = 0; kc < 8; ++kc)
            pf[kc] = *(const short8*)(const void*)&P[32 * mh + l32][16 * kc + 8 * h];
        __syncthreads();   // B3: all LDS reads done -> next staging may begin

        #pragma unroll
        for (int kc = 0; kc < 8; ++kc)
            acc = __builtin_amdgcn_mfma_f32_32x32x16_bf16(vf[kc], pf[kc], acc, 0, 0, 0);
    }

    // ---- epilogue: out = x + O (32x32 C-layout, verified R6) ----
    #pragma unroll
    for (int r = 0; r < 16; ++r) {
        const int c = 32 * ct + (r & 3) + 8 * (r >> 2) + 4 * h;
        const int m = m0 + 32 * mh + l32;
        const size_t idx = ((size_t)n * CH + c) * LL + m;
        out[idx] = x[idx] + acc[r];
    }
}

// ---------------------------------------------------------------------------
extern "C" void kernel_launch(void* const* d_in, const int* in_sizes, int n_in,
                              void* d_out, int out_size, void* d_ws, size_t ws_size,
                              hipStream_t stream) {
    (void)in_sizes; (void)n_in; (void)out_size; (void)ws_size;
    const float* x  = (const float*)d_in[0];
    const float* Wq = (const float*)d_in[1];
    const float* bq = (const float*)d_in[2];
    const float* Wk = (const float*)d_in[3];
    const float* bk = (const float*)d_in[4];
    const float* Wv = (const float*)d_in[5];
    const float* bv = (const float*)d_in[6];
    float* out = (float*)d_out;

    char* ws = (char*)d_ws;
    // ws: Qt 4MB | Kt 4MB | Vp 4MB | Dsum 64KB | Drcp 64KB  (~12.13 MB)
    short* Qt = (short*)(ws);
    short* Kt = (short*)(ws + 4194304);
    short* Vp = (short*)(ws + 8388608);
    float* Ds = (float*)(ws + 12582912);
    float* Dr = (float*)(ws + 12582912 + 65536);

    hipMemsetAsync(Ds, 0, 65536, stream);   // zero Dsum (ws is re-poisoned)
    proj_kernel<<<1024, 256, 0, stream>>>(x, Wq, bq, Wk, bk, Wv, bv, Qt, Kt, Vp);
    rowsum_kernel<<<512, 512, 0, stream>>>(Qt, Kt, Ds);
    rcp_kernel<<<64, 256, 0, stream>>>(Ds, Dr);
    attn_out_kernel<<<256, 512, 0, stream>>>(Qt, Kt, Vp, Dr, x, out);
}